// Round 7
// baseline (399.227 us; speedup 1.0000x reference)
//
#include <hip/hip_runtime.h>
#include <hip/hip_bf16.h>
#include <stdint.h>

typedef __bf16 bf16x8 __attribute__((ext_vector_type(8)));
typedef float  f32x4  __attribute__((ext_vector_type(4)));
typedef float  f32x16 __attribute__((ext_vector_type(16)));

static constexpr float kScale = 0.0078125f;  // 1/128

// ---------- f32 -> bf16 (RNE) convert, 8 elems/thread ----------
static __device__ __forceinline__ uint32_t bf16_rne(float f) {
  uint32_t u = __builtin_bit_cast(uint32_t, f);
  u += 0x7FFFu + ((u >> 16) & 1u);
  return u >> 16;
}
static __device__ __forceinline__ uint32_t pack2(float lo, float hi) {
  return bf16_rne(lo) | (bf16_rne(hi) << 16);
}

__global__ __launch_bounds__(256) void cvt_f32_to_bf16(
    const float* __restrict__ src, uint4* __restrict__ dst) {
  const int i = blockIdx.x * 256 + threadIdx.x;
  const float4* sv = reinterpret_cast<const float4*>(src);
  float4 a = sv[2 * i];
  float4 b = sv[2 * i + 1];
  uint4 o;
  o.x = pack2(a.x, a.y);
  o.y = pack2(a.z, a.w);
  o.z = pack2(b.x, b.y);
  o.w = pack2(b.z, b.w);
  dst[i] = o;
}

// ---------- async global->LDS, 16B per lane ----------
static __device__ __forceinline__ void gload_lds16(const void* g, void* l) {
  __builtin_amdgcn_global_load_lds(
      (const __attribute__((address_space(1))) void*)g,
      (__attribute__((address_space(3))) void*)l, 16, 0, 0);
}

#define BARRIER() __builtin_amdgcn_s_barrier()
#define LGKMC(n)                                               \
  do {                                                         \
    asm volatile("s_waitcnt lgkmcnt(" #n ")" ::: "memory");    \
    __builtin_amdgcn_sched_barrier(0);                         \
  } while (0)
#define VMW(n)                                                 \
  do {                                                         \
    asm volatile("s_waitcnt vmcnt(" #n ")" ::: "memory");      \
    __builtin_amdgcn_sched_barrier(0);                         \
  } while (0)

// =====================================================================
// R7: 256x256 tile, BK=32, 64B LDS rows (row parity enters bank index),
// swizzle sigma(r) = ((r>>1)&1)<<1 | ((r>>3)&1)  -> conflict-free
// ds_read_b128 (8 dwords/bank balanced, enumerated).  4 phases/tile,
// ONE barrier per phase, one-phase register read-ahead with counted
// lgkmcnt (fits VGPR: frags 48).  Stage-after-last-read choreography:
// P2: Ah0+Bh0(t+2), P3: Bh1(t+2), P4: Ah1(t+2) + VMW(4) + next-tile
// read-ahead.  LDS 64 KB.  8 waves as 2M x 4N, per-wave C = 128x64.
// =====================================================================
constexpr int TV32 = 1024;  // bf16x8 vectors per 16KB buffer (256 rows x 4)

template <int MH, int NH>
__device__ __forceinline__ void quad32(f32x16 (&acc)[4][2],
                                       const bf16x8 (&aF)[2][2],
                                       const bf16x8 (&bF)[2]) {
  __builtin_amdgcn_s_setprio(1);
#pragma unroll
  for (int ks = 0; ks < 2; ++ks)
#pragma unroll
    for (int mt = 0; mt < 2; ++mt)
      acc[MH * 2 + mt][NH] = __builtin_amdgcn_mfma_f32_32x32x16_bf16(
          aF[mt][ks], bF[ks], acc[MH * 2 + mt][NH], 0, 0, 0);
  __builtin_amdgcn_s_setprio(0);
}

// sigma_r = ((l31>>1)&1)<<1 | ((l31>>3)&1); kb = ks*2 + lk
template <int MH>
__device__ __forceinline__ void loadA32(bf16x8 (&aF)[2][2], const bf16x8* Av,
                                        int buf, int wr, int l31, int lk,
                                        int sr) {
#pragma unroll
  for (int mt = 0; mt < 2; ++mt) {
    const int row = (MH << 7) + (wr << 6) + (mt << 5) + l31;
#pragma unroll
    for (int ks = 0; ks < 2; ++ks)
      aF[mt][ks] = Av[buf * TV32 + row * 4 + (((ks << 1) | lk) ^ sr)];
  }
}
template <int NH>
__device__ __forceinline__ void loadB32(bf16x8 (&bF)[2], const bf16x8* Bv,
                                        int buf, int wc, int l31, int lk,
                                        int sr) {
  const int row = (NH << 7) + (wc << 5) + l31;
#pragma unroll
  for (int ks = 0; ks < 2; ++ks)
    bF[ks] = Bv[buf * TV32 + row * 4 + (((ks << 1) | lk) ^ sr)];
}

__global__ __launch_bounds__(512, 2) void gemm256_bk32(
    const uint16_t* __restrict__ A, const uint16_t* __restrict__ B,
    const float* __restrict__ bias, float* __restrict__ C,
    int Mi, int Ni, int Ki) {
  __shared__ __align__(16) uint16_t As[2][256 * 32];  // 16 KB each
  __shared__ __align__(16) uint16_t Bs[2][256 * 32];  // 16 KB each

  const int tid = threadIdx.x;
  const int l   = tid & 63;
  const int wv  = tid >> 6;
  const int wr  = wv >> 2;   // 0..1
  const int wc  = wv & 3;    // 0..3
  const int l31 = l & 31;
  const int lk  = l >> 5;
  const int sr  = (((l31 >> 1) & 1) << 1) | ((l31 >> 3) & 1);

  const int nbm = Mi >> 8, nbn = Ni >> 8;
  const int nwg = nbm * nbn;
  const int q = nwg >> 3, r = nwg & 7;
  const int xcd = (int)blockIdx.x & 7, orig = (int)blockIdx.x >> 3;
  const int swz = (xcd < r ? xcd * (q + 1) : r * (q + 1) + (xcd - r) * q) + orig;

  // 8bm x 4bn super-tile mapping (L2 dedup across concurrent CUs)
  int bm, bn;
  if ((nbm & 7) == 0 && (nbn & 3) == 0) {
    const int s = swz >> 5;
    const int o = swz & 31;
    const int nsc = nbn >> 2;
    bm = (s / nsc) * 8 + (o >> 2);
    bn = (s % nsc) * 4 + (o & 3);
  } else {
    bm = swz / nbn;
    bn = swz % nbn;
  }

  // staging: instr covers 16 rows; lane l -> row rho = l>>2, col c = l&3;
  // global source col-block = c ^ sigma_w, sigma_w = ((l>>3)&1)<<1 | (l>>5)
  const int sw = (((l >> 3) & 1) << 1) | ((l >> 5) & 1);
  const int srow = (l >> 2);
  const int scol = ((l & 3) ^ sw) << 3;  // elems
  const uint16_t* gA32 =
      A + (size_t)((bm << 8) + (wv << 4) + srow) * Ki + scol;
  const uint16_t* gB32 =
      B + (size_t)((bn << 8) + (wv << 4) + srow) * Ki + scol;

#define STG_A(bufi, half, t)                                      \
  gload_lds16(gA32 + (size_t)(half) * 128 * Ki + (t) * 32,        \
              &As[bufi][((half) * 128 + (wv << 4)) << 5])
#define STG_B(bufi, half, t)                                      \
  gload_lds16(gB32 + (size_t)(half) * 128 * Ki + (t) * 32,        \
              &Bs[bufi][((half) * 128 + (wv << 4)) << 5])

  const bf16x8* Av = reinterpret_cast<const bf16x8*>(&As[0][0]);
  const bf16x8* Bv = reinterpret_cast<const bf16x8*>(&Bs[0][0]);

  f32x16 acc[4][2] = {};
  bf16x8 aFA[2][2], aFB[2][2], b0[2], b1[2];

  const int NT = Ki >> 5;  // 32-K tiles (host guarantees Ki%128==0, >=256)

  // ---- prologue: stage t0 + t1, drain t0, read-ahead t0-P1 operands ----
  STG_A(0, 0, 0); STG_A(0, 1, 0); STG_B(0, 0, 0); STG_B(0, 1, 0);
  STG_A(1, 0, 1); STG_A(1, 1, 1); STG_B(1, 0, 1); STG_B(1, 1, 1);
  VMW(4);
  BARRIER();
  loadA32<0>(aFA, Av, 0, wr, l31, lk, sr);
  loadB32<0>(b0, Bv, 0, wc, l31, lk, sr);

#pragma unroll 1
  for (int t = 0; t < NT; ++t) {
    const int p = t & 1, np = p ^ 1;
    const bool st = (t + 2 < NT);
    const bool nx = (t + 1 < NT);

    // P1: Q(0,0) [aFA,b0] | read-ahead b1 (Bh1, buf p)
    loadB32<1>(b1, Bv, p, wc, l31, lk, sr);
    LGKMC(2);                       // drain aFA + b0 (6 older)
    quad32<0, 0>(acc, aFA, b0);
    BARRIER();

    // P2: Q(0,1) [aFA,b1] | stage Ah0,Bh0(t+2) | read-ahead aFB (Ah1)
    if (st) { STG_A(p, 0, t + 2); STG_B(p, 0, t + 2); }
    loadA32<1>(aFB, Av, p, wr, l31, lk, sr);
    LGKMC(4);                       // drain b1 (2 older)
    quad32<0, 1>(acc, aFA, b1);
    BARRIER();

    // P3: Q(1,0) [aFB,b0] | stage Bh1(t+2)
    if (st) STG_B(p, 1, t + 2);
    LGKMC(0);                       // drain aFB
    quad32<1, 0>(acc, aFB, b0);
    BARRIER();

    // P4: Q(1,1) [aFB,b1] | stage Ah1(t+2) | VMW | read-ahead next tile
    if (st) STG_A(p, 1, t + 2);
    if (nx) {
      if (st) { VMW(4); } else { VMW(0); }  // next-tile buffer complete
      loadA32<0>(aFA, Av, np, wr, l31, lk, sr);
      loadB32<0>(b0, Bv, np, wc, l31, lk, sr);
    }
    quad32<1, 1>(acc, aFB, b1);     // operands held; no wait needed
    BARRIER();
  }

  // ---- epilogue (32x32 C/D layout): col = lane&31, row = (reg&3) +
  // 8*(reg>>2) + 4*lk within each 32x32 tile.
  const int rowB = (bm << 8) + (wr << 6) + 4 * lk;
  const int colB = (bn << 8) + (wc << 5) + l31;
#pragma unroll
  for (int mt4 = 0; mt4 < 4; ++mt4) {
    const int rBase = rowB + (mt4 >> 1) * 128 + (mt4 & 1) * 32;
#pragma unroll
    for (int nh = 0; nh < 2; ++nh) {
      const int col = colB + nh * 128;
      const float bv = bias[col];
#pragma unroll
      for (int reg = 0; reg < 16; ++reg) {
        const int row = rBase + (reg & 3) + 8 * (reg >> 2);
        C[(size_t)row * Ni + col] = acc[mt4][nh][reg] * kScale + bv;
      }
    }
  }
}

// =====================================================================
// proven 128x128 fallback for non-conforming shapes
// =====================================================================
__global__ __launch_bounds__(256) void gemm_bf16_bias(
    const uint16_t* __restrict__ A, const uint16_t* __restrict__ B,
    const float* __restrict__ bias, float* __restrict__ C,
    int Mi, int Ni, int Ki) {
  __shared__ __align__(16) uint16_t As[128 * 32];
  __shared__ __align__(16) uint16_t Bs[128 * 32];

  const int tid  = threadIdx.x;
  const int lane = tid & 63;
  const int wv   = tid >> 6;
  const int wr   = wv >> 1;
  const int wc   = wv & 1;
  const int fr   = lane & 15;
  const int fh   = lane >> 4;

  const int nTilesN = Ni >> 7;
  const int nwg = gridDim.x;
  const int q = nwg >> 3, r = nwg & 7;
  const int xcd = (int)blockIdx.x & 7, orig = (int)blockIdx.x >> 3;
  const int swz = (xcd < r ? xcd * (q + 1) : r * (q + 1) + (xcd - r) * q) + orig;
  const int bm = swz / nTilesN;
  const int bn = swz % nTilesN;

  const int sRow = tid >> 2;
  const int sCol = (tid & 3) << 3;

  const uint16_t* gA0 = A + (size_t)(bm * 128 + sRow) * Ki + sCol;
  const uint16_t* gA1 = gA0 + (size_t)64 * Ki;
  const uint16_t* gB0 = B + (size_t)(bn * 128 + sRow) * Ki + sCol;
  const uint16_t* gB1 = gB0 + (size_t)64 * Ki;
  uint16_t* lA0 = &As[tid * 8];
  uint16_t* lA1 = &As[(256 + tid) * 8];
  uint16_t* lB0 = &Bs[tid * 8];
  uint16_t* lB1 = &Bs[(256 + tid) * 8];

  typedef __bf16 bf16x8l __attribute__((ext_vector_type(8)));
  const bf16x8l* Avl = reinterpret_cast<const bf16x8l*>(As);
  const bf16x8l* Bvl = reinterpret_cast<const bf16x8l*>(Bs);

  f32x4 acc[4][4] = {};

  for (int k0 = 0; k0 < Ki; k0 += 32) {
    gload_lds16(gA0 + k0, lA0);
    gload_lds16(gA1 + k0, lA1);
    gload_lds16(gB0 + k0, lB0);
    gload_lds16(gB1 + k0, lB1);
    __syncthreads();

    bf16x8l af[4], bfr[4];
#pragma unroll
    for (int m = 0; m < 4; ++m) af[m] = Avl[(wr * 64 + m * 16 + fr) * 4 + fh];
#pragma unroll
    for (int n = 0; n < 4; ++n) bfr[n] = Bvl[(wc * 64 + n * 16 + fr) * 4 + fh];

#pragma unroll
    for (int m = 0; m < 4; ++m)
#pragma unroll
      for (int n = 0; n < 4; ++n)
        acc[m][n] = __builtin_amdgcn_mfma_f32_16x16x32_bf16(af[m], bfr[n],
                                                            acc[m][n], 0, 0, 0);
    __syncthreads();
  }

  const int rowBase = bm * 128 + wr * 64;
  const int colBase = bn * 128 + wc * 64;
#pragma unroll
  for (int n = 0; n < 4; ++n) {
    const int col = colBase + n * 16 + fr;
    const float bv = bias[col];
#pragma unroll
    for (int m = 0; m < 4; ++m) {
      const int row = rowBase + m * 16 + fh * 4;
#pragma unroll
      for (int j = 0; j < 4; ++j)
        C[(size_t)(row + j) * Ni + col] = acc[m][n][j] * kScale + bv;
    }
  }
}

// ---------- fallback: naive f32 ----------
__global__ void naive_gemm(const float* __restrict__ x, const float* __restrict__ w,
                           const float* __restrict__ bias, float* __restrict__ out,
                           int Mi, int Ni, int Ki) {
  long idx = (long)blockIdx.x * blockDim.x + threadIdx.x;
  if (idx >= (long)Mi * Ni) return;
  int m = (int)(idx / Ni), n = (int)(idx % Ni);
  float s = 0.f;
  for (int k = 0; k < Ki; ++k) s += x[(long)m * Ki + k] * w[(long)n * Ki + k];
  out[idx] = s * kScale + bias[n];
}

extern "C" void kernel_launch(void* const* d_in, const int* in_sizes, int n_in,
                              void* d_out, int out_size, void* d_ws, size_t ws_size,
                              hipStream_t stream) {
  const float* x    = (const float*)d_in[0];
  const float* w    = (const float*)d_in[1];
  const float* bias = (const float*)d_in[2];
  float* out = (float*)d_out;

  const int Ni = in_sizes[2];
  const int Ki = in_sizes[1] / Ni;
  const int Mi = in_sizes[0] / Ki;

  const size_t nx = (size_t)Mi * Ki;
  const size_t nw = (size_t)Ni * Ki;

  if (ws_size >= (nx + nw) * sizeof(uint16_t) && (Ki % 32) == 0 &&
      (Mi % 128) == 0 && (Ni % 128) == 0) {
    uint16_t* xb = (uint16_t*)d_ws;
    uint16_t* wb = xb + nx;
    cvt_f32_to_bf16<<<(int)(nx / 2048), 256, 0, stream>>>(x, (uint4*)xb);
    cvt_f32_to_bf16<<<(int)(nw / 2048), 256, 0, stream>>>(w, (uint4*)wb);

    if ((Mi % 256) == 0 && (Ni % 256) == 0 && (Ki % 128) == 0 && Ki >= 256) {
      dim3 grid((Mi / 256) * (Ni / 256));
      gemm256_bk32<<<grid, 512, 0, stream>>>(xb, wb, bias, out, Mi, Ni, Ki);
    } else {
      dim3 grid((Mi / 128) * (Ni / 128));
      gemm_bf16_bias<<<grid, 256, 0, stream>>>(xb, wb, bias, out, Mi, Ni, Ki);
    }
  } else {
    long total = (long)Mi * Ni;
    naive_gemm<<<(int)((total + 255) / 256), 256, 0, stream>>>(x, w, bias, out,
                                                               Mi, Ni, Ki);
  }
}